// Round 9
// baseline (1879.545 us; speedup 1.0000x reference)
//
#include <hip/hip_runtime.h>

// ---------------------------------------------------------------------------
// Problem: B=128, T=256, N=512, M=512.
// softmax over a constant row == uniform 1/N => attention arm is dead code.
// Op is an LSTM with inputs scaled by 1/512.
//   xg[b,t,j] = sum_n x[b,t,n]/512 * w_ih[j,n] + b_ih[j] + b_hh[j]   (GEMM)
//   per step:  gates = xg[:,t,:] + h @ w_hh^T ; LSTM cell; out = h
//
// R7: two-chain interleave. R6's NaN signature (finite-math kernel => NaN
// only from consuming un-landed asm-load registers) indicts cross-step
// register prefetch; dropped. Instead: 8 independent batch-chains of 16;
// each wg (2 waves) runs a chain PAIR per m-group, interleaved
//   pollA -> stepA -> publishA -> pollB -> stepB -> publishB
// so each chain's publish->poll propagation (~1-2k cy) hides under the
// other chain's compute. Every load/wait/store micro-pattern inside a step
// is VERBATIM from the R2 kernel that passed (in-step xg loads, counted
// VMCNT(24)/(16)/(0), sc0sc1 h exchange, central per-group RMW counter,
// fire-and-forget publish, tid0 poll + s_barrier). No cross-step asm regs.
// ---------------------------------------------------------------------------

typedef __attribute__((ext_vector_type(8))) __bf16 bf16x8;
typedef __attribute__((ext_vector_type(8))) unsigned short u16x8;
typedef __attribute__((ext_vector_type(4))) float f32x4;
typedef unsigned short ushort_t;

__device__ __forceinline__ unsigned short f2b(float f) {
  unsigned u = __builtin_bit_cast(unsigned, f);
  unsigned r = (u + 0x7FFFu + ((u >> 16) & 1u)) >> 16;
  return (unsigned short)r;
}
__device__ __forceinline__ float b2f(unsigned short s) {
  unsigned u = ((unsigned)s) << 16;
  return __builtin_bit_cast(float, u);
}
__device__ __forceinline__ float sigm(float x) { return 1.0f / (1.0f + __expf(-x)); }
__device__ __forceinline__ float tanh_f(float x) { return 1.0f - 2.0f / (__expf(2.0f * x) + 1.0f); }

#define VMCNT(n) asm volatile("s_waitcnt vmcnt(" #n ")" ::: "memory")

// Coherent (Infinity-Cache-level) accesses: sc0 sc1 bypass L1 and the
// non-coherent per-XCD L2 on both sides (proven in R2).
__device__ __forceinline__ void hload16(f32x4* dst, const ushort_t* p) {
  asm volatile("global_load_dwordx4 %0, %1, off sc0 sc1"
               : "=v"(*dst) : "v"(p) : "memory");
}
__device__ __forceinline__ void hstore2(ushort_t* p, unsigned v) {
  asm volatile("global_store_short %0, %1, off sc0 sc1"
               :: "v"(p), "v"(v) : "memory");
}
__device__ __forceinline__ void xload_f32(unsigned* dst, const float* p) {
  asm volatile("global_load_dword %0, %1, off" : "=v"(*dst) : "v"(p) : "memory");
}
__device__ __forceinline__ void xload_bf(unsigned* dst, const ushort_t* p) {
  asm volatile("global_load_ushort %0, %1, off" : "=v"(*dst) : "v"(p) : "memory");
}

// ---------------------------------------------------------------------------
// Kernel 1: convert inputs -> bf16 (scaled 1/512), w_ih -> bf16, bias sum.
// ---------------------------------------------------------------------------
__global__ __launch_bounds__(256) void convert_kernel(
    const float* __restrict__ inp, const float* __restrict__ wih,
    const float* __restrict__ bih, const float* __restrict__ bhh,
    ushort_t* __restrict__ X, ushort_t* __restrict__ W, float* __restrict__ bias)
{
  int tid = blockIdx.x * 256 + threadIdx.x;
  int stride = gridDim.x * 256;
  const float s = 1.0f / 512.0f;
  for (int i = tid; i < (16777216 / 4); i += stride) {
    float4 v = reinterpret_cast<const float4*>(inp)[i];
    ushort4 o; o.x = f2b(v.x * s); o.y = f2b(v.y * s); o.z = f2b(v.z * s); o.w = f2b(v.w * s);
    reinterpret_cast<ushort4*>(X)[i] = o;
  }
  for (int i = tid; i < (1048576 / 4); i += stride) {
    float4 v = reinterpret_cast<const float4*>(wih)[i];
    ushort4 o; o.x = f2b(v.x); o.y = f2b(v.y); o.z = f2b(v.z); o.w = f2b(v.w);
    reinterpret_cast<ushort4*>(W)[i] = o;
  }
  for (int i = tid; i < 2048; i += stride) bias[i] = bih[i] + bhh[i];
}

// ---------------------------------------------------------------------------
// Kernel 2: xg GEMM. C[32768,2048] = X[32768,512](bf16) @ W[2048,512]^T + bias.
// ---------------------------------------------------------------------------
template<bool XGBF>
__global__ __launch_bounds__(256) void gemm_xg_kernel(
    const ushort_t* __restrict__ X, const ushort_t* __restrict__ W,
    const float* __restrict__ bias, void* __restrict__ xg)
{
  __shared__ bf16x8 AsV[1024];
  __shared__ bf16x8 BsV[1024];
  ushort_t* As = (ushort_t*)AsV;
  ushort_t* Bs = (ushort_t*)BsV;

  int tid = threadIdx.x;
  int lane = tid & 63;
  int wv = tid >> 6;
  int wr = wv >> 1, wc = wv & 1;
  int ll = lane & 15;
  int kg = lane >> 4;
  int bm = blockIdx.x & 255;
  int bn = blockIdx.x >> 8;

  f32x4 acc[4][4];
#pragma unroll
  for (int i = 0; i < 4; ++i)
#pragma unroll
    for (int j = 0; j < 4; ++j) acc[i][j] = (f32x4){0.f, 0.f, 0.f, 0.f};

  for (int kt = 0; kt < 8; ++kt) {
#pragma unroll
    for (int it = 0; it < 4; ++it) {
      int i = it * 256 + tid;
      int row = i >> 3, ch = i & 7;
      int de = row * 64 + ((ch ^ (row & 7)) << 3);
      *reinterpret_cast<bf16x8*>(As + de) =
          *reinterpret_cast<const bf16x8*>(X + (size_t)(bm * 128 + row) * 512 + kt * 64 + ch * 8);
      *reinterpret_cast<bf16x8*>(Bs + de) =
          *reinterpret_cast<const bf16x8*>(W + (size_t)(bn * 128 + row) * 512 + kt * 64 + ch * 8);
    }
    __syncthreads();
#pragma unroll
    for (int kc = 0; kc < 2; ++kc) {
      int kch = kc * 4 + kg;
      bf16x8 a[4], b[4];
#pragma unroll
      for (int fi = 0; fi < 4; ++fi) {
        int row = wr * 64 + fi * 16 + ll;
        a[fi] = *reinterpret_cast<const bf16x8*>(As + row * 64 + ((kch ^ (row & 7)) << 3));
      }
#pragma unroll
      for (int fj = 0; fj < 4; ++fj) {
        int row = wc * 64 + fj * 16 + ll;
        b[fj] = *reinterpret_cast<const bf16x8*>(Bs + row * 64 + ((kch ^ (row & 7)) << 3));
      }
#pragma unroll
      for (int fi = 0; fi < 4; ++fi)
#pragma unroll
        for (int fj = 0; fj < 4; ++fj)
          acc[fi][fj] = __builtin_amdgcn_mfma_f32_16x16x32_bf16(a[fi], b[fj], acc[fi][fj], 0, 0, 0);
    }
    __syncthreads();
  }
#pragma unroll
  for (int fj = 0; fj < 4; ++fj) {
    int colj = bn * 128 + wc * 64 + fj * 16 + ll;
    float bv = bias[colj];
#pragma unroll
    for (int fi = 0; fi < 4; ++fi)
#pragma unroll
      for (int r = 0; r < 4; ++r) {
        int rowi = bm * 128 + wr * 64 + fi * 16 + kg * 4 + r;
        float v = acc[fi][fj][r] + bv;
        if constexpr (XGBF) ((ushort_t*)xg)[(size_t)rowi * 2048 + colj] = f2b(v);
        else                ((float*)xg)[(size_t)rowi * 2048 + colj] = v;
      }
  }
}

// ---------------------------------------------------------------------------
// Kernel 3: one chain step (R2 micro-patterns verbatim).
// poll(ctr >= 16*t) -> [16 h loads + 16 xg loads, VMCNT(24)/(16) MFMA,
// VMCNT(0), gates, h stores, VMCNT(0)] -> publish(add) -> out stores.
// ---------------------------------------------------------------------------
template<bool XGBF>
__device__ __forceinline__ void chain_step(
    int t, const bf16x8 (&bfr)[4][16], float (&c)[4],
    ushort_t* hbuf, float* out, const void* xg, unsigned* ctr,
    int b0, int m0, int ll, int kg, int tid)
{
  // ---- poll: h(t) ready when all 16 wgs of this group published step t-1 ----
  if (tid == 0) {
    unsigned tgt = 16u * (unsigned)t;
    unsigned guard = 0;
    while (__hip_atomic_load(ctr, __ATOMIC_RELAXED, __HIP_MEMORY_SCOPE_AGENT) < tgt) {
      if (++guard > (1u << 15)) break;      // valve: terminate, don't hang
      __builtin_amdgcn_s_sleep(1);
    }
  }
  __builtin_amdgcn_s_barrier();

  // ---- issue 16 h loads (coherent) + 16 xg loads (plain, in-step) ----
  const ushort_t* hrow = hbuf + (size_t)(t & 1) * 65536 + (size_t)(b0 + ll) * 512 + kg * 8;
  f32x4 hraw[16];
#pragma unroll
  for (int ks = 0; ks < 16; ++ks) hload16(&hraw[ks], hrow + ks * 32);

  size_t lanebase = (size_t)(b0 + kg * 4) * 524288 + (size_t)t * 2048 + m0 + ll;
  unsigned xv[16];
#pragma unroll
  for (int g = 0; g < 4; ++g)
#pragma unroll
    for (int r = 0; r < 4; ++r) {
      size_t off = lanebase + (size_t)r * 524288 + g * 512;
      if constexpr (XGBF) xload_bf(&xv[g * 4 + r], (const ushort_t*)xg + off);
      else                xload_f32(&xv[g * 4 + r], (const float*)xg + off);
    }

  // ---- MFMA as h loads land. Queue (oldest->newest): [<=5 stale stores
  // (prev publish add + 4 out)][16 h][16 xg]; VMCNT(24) -> h[0..7] done,
  // VMCNT(16) -> all h done (in-order retirement; stale ops only stricter) ----
  f32x4 acc[4];
#pragma unroll
  for (int g = 0; g < 4; ++g) acc[g] = (f32x4){0.f, 0.f, 0.f, 0.f};
  VMCNT(24);
  __builtin_amdgcn_sched_barrier(0);
#pragma unroll
  for (int ks = 0; ks < 8; ++ks) {
    bf16x8 a = __builtin_bit_cast(bf16x8, hraw[ks]);
#pragma unroll
    for (int g = 0; g < 4; ++g)
      acc[g] = __builtin_amdgcn_mfma_f32_16x16x32_bf16(a, bfr[g][ks], acc[g], 0, 0, 0);
  }
  VMCNT(16);
  __builtin_amdgcn_sched_barrier(0);
#pragma unroll
  for (int ks = 8; ks < 16; ++ks) {
    bf16x8 a = __builtin_bit_cast(bf16x8, hraw[ks]);
#pragma unroll
    for (int g = 0; g < 4; ++g)
      acc[g] = __builtin_amdgcn_mfma_f32_16x16x32_bf16(a, bfr[g][ks], acc[g], 0, 0, 0);
  }
  VMCNT(0);                                  // xg landed
  __builtin_amdgcn_sched_barrier(0);

  // ---- gates + state update; coherent per-ushort h stores ----
  ushort_t* hw = hbuf + (size_t)((t + 1) & 1) * 65536;
  float hv[4];
#pragma unroll
  for (int r = 0; r < 4; ++r) {
    float x0, x1, x2, x3;
    if constexpr (XGBF) {
      x0 = b2f((ushort_t)xv[0 * 4 + r]); x1 = b2f((ushort_t)xv[1 * 4 + r]);
      x2 = b2f((ushort_t)xv[2 * 4 + r]); x3 = b2f((ushort_t)xv[3 * 4 + r]);
    } else {
      x0 = __builtin_bit_cast(float, xv[0 * 4 + r]); x1 = __builtin_bit_cast(float, xv[1 * 4 + r]);
      x2 = __builtin_bit_cast(float, xv[2 * 4 + r]); x3 = __builtin_bit_cast(float, xv[3 * 4 + r]);
    }
    float ig = sigm(acc[0][r] + x0);
    float fg = sigm(acc[1][r] + x1);
    float gg = tanh_f(acc[2][r] + x2);
    float og = sigm(acc[3][r] + x3);
    c[r] = fg * c[r] + ig * gg;
    hv[r] = og * tanh_f(c[r]);
    hstore2(hw + (size_t)(b0 + kg * 4 + r) * 512 + m0 + ll, (unsigned)f2b(hv[r]));
  }

  // ---- drain h stores, publish (fire-and-forget add), out stores ----
  VMCNT(0);
  __builtin_amdgcn_sched_barrier(0);
  __builtin_amdgcn_s_barrier();              // all waves of wg drained
  if (tid == 0)
    __hip_atomic_fetch_add(ctr, 1u, __ATOMIC_RELAXED, __HIP_MEMORY_SCOPE_AGENT);
#pragma unroll
  for (int r = 0; r < 4; ++r)
    __builtin_nontemporal_store(hv[r], out + ((size_t)(b0 + kg * 4 + r) * 256 + t) * 512 + m0 + ll);
}

// ---------------------------------------------------------------------------
// Kernel 3: persistent LSTM recurrence, two interleaved chains per wg.
// 64 wgs x 128 thr (2 waves). wg = m-group (32 m) x chain pair:
// chain A rows [pr*32, pr*32+16), chain B rows [pr*32+16, pr*32+32).
// Chain A's publish->poll latency hides under chain B's compute & v.v.
// ---------------------------------------------------------------------------
template<bool XGBF>
__global__ __launch_bounds__(128, 1) void lstm_rec_kernel(
    const float* __restrict__ whh, const void* __restrict__ xg,
    ushort_t* __restrict__ hbuf /*[2][128][512] bf16*/, float* __restrict__ out,
    unsigned* __restrict__ ctrs /*8 counters, 128B apart*/)
{
  int tid = threadIdx.x;
  int lane = tid & 63;
  int wvm = tid >> 6;            // 2 waves split the 32-m range
  int gm = blockIdx.x & 15;      // m-group
  int pr = blockIdx.x >> 4;      // chain pair 0..3
  int ll = lane & 15, kg = lane >> 4;
  int m0 = gm * 32 + wvm * 16;
  int b0A = pr * 32;             // chain 2*pr
  int b0B = pr * 32 + 16;        // chain 2*pr+1
  unsigned* ctrA = ctrs + (pr * 2) * 32;
  unsigned* ctrB = ctrs + (pr * 2 + 1) * 32;

  // preload w_hh fragments -> registers (fp32 read once, cvt to bf16)
  bf16x8 bfr[4][16];
#pragma unroll
  for (int g = 0; g < 4; ++g) {
    const float* wrow = whh + (size_t)(g * 512 + m0 + ll) * 512;
#pragma unroll
    for (int ks = 0; ks < 16; ++ks) {
      const float4* wp = reinterpret_cast<const float4*>(wrow + ks * 32 + kg * 8);
      float4 lo = wp[0], hi = wp[1];
      u16x8 tbits;
      tbits[0] = f2b(lo.x); tbits[1] = f2b(lo.y); tbits[2] = f2b(lo.z); tbits[3] = f2b(lo.w);
      tbits[4] = f2b(hi.x); tbits[5] = f2b(hi.y); tbits[6] = f2b(hi.z); tbits[7] = f2b(hi.w);
      bfr[g][ks] = __builtin_bit_cast(bf16x8, tbits);
    }
  }

  float cA[4] = {0.f, 0.f, 0.f, 0.f};
  float cB[4] = {0.f, 0.f, 0.f, 0.f};

  for (int t = 0; t < 256; ++t) {
    chain_step<XGBF>(t, bfr, cA, hbuf, out, xg, ctrA, b0A, m0, ll, kg, tid);
    chain_step<XGBF>(t, bfr, cB, hbuf, out, xg, ctrB, b0B, m0, ll, kg, tid);
  }
}

// ---------------------------------------------------------------------------
extern "C" void kernel_launch(void* const* d_in, const int* in_sizes, int n_in,
                              void* d_out, int out_size, void* d_ws, size_t ws_size,
                              hipStream_t stream)
{
  const float* inputs = (const float*)d_in[0];
  // d_in[1..3] = W_e_w, W_e_b, U_e_w : dead (softmax of constant row)
  const float* w_ih = (const float*)d_in[4];
  const float* w_hh = (const float*)d_in[5];
  const float* b_ih = (const float*)d_in[6];
  const float* b_hh = (const float*)d_in[7];
  float* out = (float*)d_out;
  char* ws = (char*)d_ws;

  const size_t xg_f32_bytes = (size_t)32768 * 2048 * 4;  // 268.4 MB
  const size_t xg_bf_bytes  = (size_t)32768 * 2048 * 2;  // 134.2 MB
  const size_t xbytes = (size_t)16777216 * 2;            // X bf16
  const size_t wbytes = (size_t)1048576 * 2;             // w_ih bf16
  const size_t biasb  = 2048 * 4;
  const size_t hbytes = (size_t)2 * 128 * 512 * 2;       // h double buffer
  const size_t ctrb   = 1024;                            // 8 counters, 128B apart
  const size_t tail = xbytes + wbytes + biasb + hbytes + ctrb + 1024;

  bool f32p = ws_size >= xg_f32_bytes + tail;            // adaptive xg precision
  size_t xgb  = f32p ? xg_f32_bytes : xg_bf_bytes;
  size_t oX   = xgb;
  size_t oW   = oX + xbytes;
  size_t oB   = oW + wbytes;
  size_t oH   = (oB + biasb + 255) & ~(size_t)255;
  size_t oC   = oH + hbytes;

  hipMemsetAsync(ws + oH, 0, hbytes + ctrb, stream);     // zero h0 + counters

  convert_kernel<<<2048, 256, 0, stream>>>(inputs, w_ih, b_ih, b_hh,
      (ushort_t*)(ws + oX), (ushort_t*)(ws + oW), (float*)(ws + oB));

  if (f32p) {
    gemm_xg_kernel<false><<<4096, 256, 0, stream>>>(
        (const ushort_t*)(ws + oX), (const ushort_t*)(ws + oW), (const float*)(ws + oB), ws);
    lstm_rec_kernel<false><<<64, 128, 0, stream>>>(
        w_hh, ws, (ushort_t*)(ws + oH), out, (unsigned*)(ws + oC));
  } else {
    gemm_xg_kernel<true><<<4096, 256, 0, stream>>>(
        (const ushort_t*)(ws + oX), (const ushort_t*)(ws + oW), (const float*)(ws + oB), ws);
    lstm_rec_kernel<true><<<64, 128, 0, stream>>>(
        w_hh, ws, (ushort_t*)(ws + oH), out, (unsigned*)(ws + oC));
  }
  (void)in_sizes; (void)n_in; (void)out_size;
}